// Round 1
// baseline (2692.092 us; speedup 1.0000x reference)
//
#include <hip/hip_runtime.h>

// RNN encoder: h_{t+1} = relu([x_t, h_t] @ W^T + b)
// B=4096, T=35, U=1024, K=2048.  W (1024x2048) row-major == [Wx | Wh] K-concat.
// Per step: one TN GEMM M=4096 N=1024 K=2048, bf16 MFMA, fp32 accumulate.

typedef __bf16 bf16;
typedef __bf16 bf16x8 __attribute__((ext_vector_type(8)));
typedef __bf16 bf16x4 __attribute__((ext_vector_type(4)));
typedef float f32x4 __attribute__((ext_vector_type(4)));

#define B_N 4096
#define T_N 35
#define U_N 1024
#define K_N 2048
#define XROW (T_N * U_N)   // elements per batch row of x

// generic -> address-space casts for global_load_lds
#define AS1CP(p) ((const __attribute__((address_space(1))) void*)(p))
#define AS3CP(p) ((__attribute__((address_space(3))) void*)(p))

__global__ __launch_bounds__(256) void w_to_bf16(const float* __restrict__ W,
                                                 bf16* __restrict__ Wb) {
  int i = (blockIdx.x * 256 + threadIdx.x) * 4;
  f32x4 f = *(const f32x4*)(W + i);
  bf16x4 o = { (bf16)f.x, (bf16)f.y, (bf16)f.z, (bf16)f.w };
  *(bf16x4*)(Wb + i) = o;
}

// One time step: C = relu(A @ Wb^T + b), A = [x_t (fp32->bf16) | hin (bf16)]
// Tile: 128x128 per block, 256 threads = 4 waves in 2x2, each wave 64x64
// via 4x4 grid of 16x16x32 bf16 MFMAs.  BK=32.
__global__ __launch_bounds__(256) void rnn_step(
    const float* __restrict__ x,   // (B, T, U)
    int t,
    const bf16* __restrict__ Wb,   // (U, 2U) row-major, K-contiguous
    const bf16* __restrict__ hin,  // (B, U)
    const float* __restrict__ bias,// (U)
    bf16* __restrict__ hout,       // (B, U)
    float* __restrict__ out)       // null, or (B, U) fp32 on last step
{
  __shared__ bf16 As[128 * 32];  // 8 KB, row-major 128 rows x 32 k
  __shared__ bf16 Bs[128 * 32];  // 8 KB

  const int tid  = threadIdx.x;
  const int w    = tid >> 6;   // wave 0..3
  const int l    = tid & 63;   // lane
  const int row0 = blockIdx.x * 128;  // batch rows
  const int col0 = blockIdx.y * 128;  // unit cols
  const int wm   = w & 1;      // wave's 64-row quadrant
  const int wn   = w >> 1;     // wave's 64-col quadrant

  const int lq = l >> 4;       // 0..3
  const int lm = l & 15;       // fragment row/col within 16
  const int lk = lq * 8;       // fragment k offset within 32

  // async staging pattern: lane l covers row (base + l/4), 16B chunk (l&3)
  const int arow = w * 32;     // each wave stages 32 rows (2 insts of 16)
  const int srow = l >> 2;
  const int scol = (l & 3) * 8;

  f32x4 acc[4][4] = {};

  // ---- Phase 1: k in [0,1024) — A from x (fp32 -> bf16 in regs) ----
  for (int kk = 0; kk < 1024; kk += 32) {
    // B tile: Wb[col0..col0+127][kk..kk+31] via async 16B direct-to-LDS
#pragma unroll
    for (int r = 0; r < 2; ++r) {
      int nr = arow + r * 16;
      const bf16* g = Wb + (size_t)(col0 + nr + srow) * K_N + kk + scol;
      __builtin_amdgcn_global_load_lds(AS1CP(g), AS3CP(Bs + nr * 32), 16, 0, 0);
    }
    // A tile: 128x32 fp32 -> bf16, 256 threads x 2 chunks of 8
#pragma unroll
    for (int r = 0; r < 2; ++r) {
      int c   = tid + r * 256;       // 0..511
      int row = c >> 2;              // 0..127
      int cc  = (c & 3) * 8;
      const float* g = x + (size_t)(row0 + row) * XROW + (size_t)t * U_N + kk + cc;
      f32x4 f0 = *(const f32x4*)g;
      f32x4 f1 = *(const f32x4*)(g + 4);
      bf16x8 v = { (bf16)f0.x, (bf16)f0.y, (bf16)f0.z, (bf16)f0.w,
                   (bf16)f1.x, (bf16)f1.y, (bf16)f1.z, (bf16)f1.w };
      *(bf16x8*)(As + row * 32 + cc) = v;
    }
    __syncthreads();

    bf16x8 af[4], bfr[4];
#pragma unroll
    for (int mi = 0; mi < 4; ++mi)
      af[mi] = *(const bf16x8*)(As + (wm * 64 + mi * 16 + lm) * 32 + lk);
#pragma unroll
    for (int ni = 0; ni < 4; ++ni)
      bfr[ni] = *(const bf16x8*)(Bs + (wn * 64 + ni * 16 + lm) * 32 + lk);
#pragma unroll
    for (int mi = 0; mi < 4; ++mi)
#pragma unroll
      for (int ni = 0; ni < 4; ++ni)
        acc[mi][ni] = __builtin_amdgcn_mfma_f32_16x16x32_bf16(af[mi], bfr[ni],
                                                              acc[mi][ni], 0, 0, 0);
    __syncthreads();
  }

  // ---- Phase 2: k in [1024,2048) — A from hin (bf16, async) ----
  for (int kk = 1024; kk < 2048; kk += 32) {
#pragma unroll
    for (int r = 0; r < 2; ++r) {
      int nr = arow + r * 16;
      const bf16* g = Wb + (size_t)(col0 + nr + srow) * K_N + kk + scol;
      __builtin_amdgcn_global_load_lds(AS1CP(g), AS3CP(Bs + nr * 32), 16, 0, 0);
    }
#pragma unroll
    for (int r = 0; r < 2; ++r) {
      int nr = arow + r * 16;
      const bf16* g = hin + (size_t)(row0 + nr + srow) * U_N + (kk - 1024) + scol;
      __builtin_amdgcn_global_load_lds(AS1CP(g), AS3CP(As + nr * 32), 16, 0, 0);
    }
    __syncthreads();

    bf16x8 af[4], bfr[4];
#pragma unroll
    for (int mi = 0; mi < 4; ++mi)
      af[mi] = *(const bf16x8*)(As + (wm * 64 + mi * 16 + lm) * 32 + lk);
#pragma unroll
    for (int ni = 0; ni < 4; ++ni)
      bfr[ni] = *(const bf16x8*)(Bs + (wn * 64 + ni * 16 + lm) * 32 + lk);
#pragma unroll
    for (int mi = 0; mi < 4; ++mi)
#pragma unroll
      for (int ni = 0; ni < 4; ++ni)
        acc[mi][ni] = __builtin_amdgcn_mfma_f32_16x16x32_bf16(af[mi], bfr[ni],
                                                              acc[mi][ni], 0, 0, 0);
    __syncthreads();
  }

  // ---- Epilogue: bias + relu; bf16 h for next step; fp32 out on last ----
  // D mapping (verified m89/m91): lane l, reg i -> row m=(l>>4)*4+i, col n=l&15
#pragma unroll
  for (int ni = 0; ni < 4; ++ni) {
    int col = col0 + wn * 64 + ni * 16 + lm;
    float bv = bias[col];
#pragma unroll
    for (int mi = 0; mi < 4; ++mi) {
#pragma unroll
      for (int i = 0; i < 4; ++i) {
        int row = row0 + wm * 64 + mi * 16 + lq * 4 + i;
        float v = acc[mi][ni][i] + bv;
        v = v > 0.f ? v : 0.f;
        hout[(size_t)row * U_N + col] = (bf16)v;
        if (out) out[(size_t)row * U_N + col] = v;
      }
    }
  }
}

extern "C" void kernel_launch(void* const* d_in, const int* in_sizes, int n_in,
                              void* d_out, int out_size, void* d_ws, size_t ws_size,
                              hipStream_t stream) {
  const float* x    = (const float*)d_in[0];
  const float* W    = (const float*)d_in[1];
  const float* bias = (const float*)d_in[2];
  float* out = (float*)d_out;

  char* ws = (char*)d_ws;
  bf16* Wb = (bf16*)ws;                              // 4 MB: (1024, 2048) bf16
  bf16* h0 = (bf16*)(ws + (size_t)4 * 1024 * 1024);  // 8 MB: (4096, 1024) bf16
  bf16* h1 = (bf16*)(ws + (size_t)12 * 1024 * 1024); // 8 MB

  // convert W once per call (2M elems / 4 per thread)
  w_to_bf16<<<2048, 256, 0, stream>>>(W, Wb);
  // h0 = 0 (ws is re-poisoned before every timed call)
  hipMemsetAsync(h0, 0, (size_t)B_N * U_N * sizeof(bf16), stream);

  bf16* bufs[2] = { h0, h1 };
  dim3 grid(32, 8);  // M/128 x N/128
  for (int t = 0; t < T_N; ++t) {
    bf16* hin  = bufs[t & 1];
    bf16* hout = bufs[(t + 1) & 1];
    float* o   = (t == T_N - 1) ? out : nullptr;
    rnn_step<<<grid, dim3(256), 0, stream>>>(x, t, Wb, hin, bias, hout, o);
  }
}

// Round 2
// 2239.260 us; speedup vs baseline: 1.2022x; 1.2022x over previous
//
#include <hip/hip_runtime.h>

// RNN encoder restructured:
//   Z[t] = x_t @ Wx^T + b     -- one big GEMM, M=143360, N=1024, K=1024 (parallel)
//   h_{t+1} = relu(Z[t] + h_t @ Wh^T)   -- 35 small GEMMs, M=4096, N=1024, K=1024
// All MFMA bf16 16x16x32, fp32 accumulate. LDS XOR-swizzled (c ^ (row&7)).

typedef __bf16 bf16;
typedef __bf16 bf16x8 __attribute__((ext_vector_type(8)));
typedef __bf16 bf16x4 __attribute__((ext_vector_type(4)));
typedef float f32x4 __attribute__((ext_vector_type(4)));

#define B_N 4096
#define T_N 35
#define U_N 1024
#define XROW (T_N * U_N)
#define BU (B_N * U_N)

#define AS1CP(p) ((const __attribute__((address_space(1))) void*)(p))
#define AS3CP(p) ((__attribute__((address_space(3))) void*)(p))

// ---- pack W (1024 x 2048 fp32) into Wxb, Whb (1024 x 1024 bf16 each) ----
__global__ __launch_bounds__(256) void pack_w(const float* __restrict__ W,
                                              bf16* __restrict__ Wxb,
                                              bf16* __restrict__ Whb) {
  int i = (blockIdx.x * 256 + threadIdx.x) * 4;  // over 1024*1024
  int n = i >> 10, k = i & 1023;
  f32x4 a = *(const f32x4*)(W + (size_t)n * 2048 + k);
  f32x4 b = *(const f32x4*)(W + (size_t)n * 2048 + 1024 + k);
  bf16x4 av = { (bf16)a.x, (bf16)a.y, (bf16)a.z, (bf16)a.w };
  bf16x4 bv = { (bf16)b.x, (bf16)b.y, (bf16)b.z, (bf16)b.w };
  *(bf16x4*)(Wxb + i) = av;
  *(bf16x4*)(Whb + i) = bv;
}

// ---- Z GEMM: tile 128x128, 256 thr (4 waves 2x2, wave 64x64), BK=64 ----
// grid: (8 col-tiles, 1120 row-tiles); row-tile mt: t = mt>>5, b0 = (mt&31)*128
__global__ __launch_bounds__(256) void z_gemm(
    const float* __restrict__ x, const bf16* __restrict__ Wxb,
    const float* __restrict__ bias, bf16* __restrict__ Zb)
{
  __shared__ bf16 As[128 * 64];  // 16 KB
  __shared__ bf16 Bs[128 * 64];  // 16 KB

  const int tid = threadIdx.x;
  const int w = tid >> 6, l = tid & 63;
  const int mt = blockIdx.y;
  const int t = mt >> 5;
  const int row0 = (mt & 31) << 7;
  const int col0 = blockIdx.x << 7;
  const int wm = w & 1, wn = w >> 1;
  const int lq = l >> 4, lm = l & 15;
  const int lrow8 = l >> 3, lc = l & 7;
  const int clog = lc ^ lrow8;  // logical chunk this lane fetches (swizzle)

  f32x4 acc[4][4] = {};
  const float* xbase = x + (size_t)row0 * XROW + (size_t)t * U_N;

  for (int kk = 0; kk < 1024; kk += 64) {
    // B tile: Wxb[col0..+127][kk..+63] via async 16B, swizzled on global side
#pragma unroll
    for (int r = 0; r < 4; ++r) {
      int nr = w * 32 + r * 8;  // multiple of 8 -> row&7 == lrow8
      const bf16* g = Wxb + (size_t)(col0 + nr + lrow8) * U_N + kk + clog * 8;
      __builtin_amdgcn_global_load_lds(AS1CP(g), AS3CP(Bs + nr * 64), 16, 0, 0);
    }
    // A tile: x fp32 -> bf16; 8 threads per row (256B contiguous per row)
#pragma unroll
    for (int i = 0; i < 4; ++i) {
      int row = i * 32 + (tid >> 3);
      int c = tid & 7;
      const float* g = xbase + (size_t)row * XROW + kk + c * 8;
      f32x4 f0 = *(const f32x4*)g;
      f32x4 f1 = *(const f32x4*)(g + 4);
      bf16x8 v = { (bf16)f0.x, (bf16)f0.y, (bf16)f0.z, (bf16)f0.w,
                   (bf16)f1.x, (bf16)f1.y, (bf16)f1.z, (bf16)f1.w };
      *(bf16x8*)(As + row * 64 + ((c ^ (row & 7)) << 3)) = v;
    }
    __syncthreads();

#pragma unroll
    for (int kq = 0; kq < 2; ++kq) {
      bf16x8 af[4], bfr[4];
#pragma unroll
      for (int mi = 0; mi < 4; ++mi) {
        int r = wm * 64 + mi * 16 + lm;
        af[mi] = *(const bf16x8*)(As + r * 64 + (((kq * 4 + lq) ^ (r & 7)) << 3));
      }
#pragma unroll
      for (int ni = 0; ni < 4; ++ni) {
        int r = wn * 64 + ni * 16 + lm;
        bfr[ni] = *(const bf16x8*)(Bs + r * 64 + (((kq * 4 + lq) ^ (r & 7)) << 3));
      }
#pragma unroll
      for (int mi = 0; mi < 4; ++mi)
#pragma unroll
        for (int ni = 0; ni < 4; ++ni)
          acc[mi][ni] = __builtin_amdgcn_mfma_f32_16x16x32_bf16(af[mi], bfr[ni],
                                                                acc[mi][ni], 0, 0, 0);
    }
    __syncthreads();
  }

  // epilogue: Zb[t][row][col] = acc + bias (no relu here)
#pragma unroll
  for (int ni = 0; ni < 4; ++ni) {
    int col = col0 + wn * 64 + ni * 16 + lm;
    float bv = bias[col];
#pragma unroll
    for (int mi = 0; mi < 4; ++mi) {
      int rbase = row0 + wm * 64 + mi * 16 + lq * 4;
#pragma unroll
      for (int i = 0; i < 4; ++i)
        Zb[(size_t)t * BU + (size_t)(rbase + i) * U_N + col] = (bf16)(acc[mi][ni][i] + bv);
    }
  }
}

// ---- recurrent step: tile 128x64, 256 thr (4 waves 2x2, wave 64x32), BK=64 ----
// grid: (16 col-tiles, 32 row-tiles) = 512 blocks -> 2 blocks/CU, 8 waves/CU
__global__ __launch_bounds__(256) void rnn_step(
    const bf16* __restrict__ hin, const bf16* __restrict__ Whb,
    const bf16* __restrict__ Zt, bf16* __restrict__ hout,
    float* __restrict__ out)
{
  __shared__ bf16 As[128 * 64];  // h tile, 16 KB
  __shared__ bf16 Bs[64 * 64];   // Wh tile, 8 KB

  const int tid = threadIdx.x;
  const int w = tid >> 6, l = tid & 63;
  const int col0 = blockIdx.x << 6;
  const int row0 = blockIdx.y << 7;
  const int wm = w & 1, wn = w >> 1;  // wave tile 64M x 32N
  const int lq = l >> 4, lm = l & 15;
  const int lrow8 = l >> 3, lc = l & 7;
  const int clog = lc ^ lrow8;

  f32x4 acc[4][2] = {};

  for (int kk = 0; kk < 1024; kk += 64) {
    // A: hin[row0..+127][kk..+63], 16 insts, 4 per wave
#pragma unroll
    for (int r = 0; r < 4; ++r) {
      int nr = w * 32 + r * 8;
      const bf16* g = hin + (size_t)(row0 + nr + lrow8) * U_N + kk + clog * 8;
      __builtin_amdgcn_global_load_lds(AS1CP(g), AS3CP(As + nr * 64), 16, 0, 0);
    }
    // B: Whb[col0..+63][kk..+63], 8 insts, 2 per wave
#pragma unroll
    for (int r = 0; r < 2; ++r) {
      int nr = w * 16 + r * 8;
      const bf16* g = Whb + (size_t)(col0 + nr + lrow8) * U_N + kk + clog * 8;
      __builtin_amdgcn_global_load_lds(AS1CP(g), AS3CP(Bs + nr * 64), 16, 0, 0);
    }
    __syncthreads();

#pragma unroll
    for (int kq = 0; kq < 2; ++kq) {
      bf16x8 af[4], bfr[2];
#pragma unroll
      for (int mi = 0; mi < 4; ++mi) {
        int r = wm * 64 + mi * 16 + lm;
        af[mi] = *(const bf16x8*)(As + r * 64 + (((kq * 4 + lq) ^ (r & 7)) << 3));
      }
#pragma unroll
      for (int ni = 0; ni < 2; ++ni) {
        int r = wn * 32 + ni * 16 + lm;
        bfr[ni] = *(const bf16x8*)(Bs + r * 64 + (((kq * 4 + lq) ^ (r & 7)) << 3));
      }
#pragma unroll
      for (int mi = 0; mi < 4; ++mi)
#pragma unroll
        for (int ni = 0; ni < 2; ++ni)
          acc[mi][ni] = __builtin_amdgcn_mfma_f32_16x16x32_bf16(af[mi], bfr[ni],
                                                                acc[mi][ni], 0, 0, 0);
    }
    __syncthreads();
  }

  // epilogue: h' = relu(Z + acc); write bf16 h, fp32 out on last step
#pragma unroll
  for (int ni = 0; ni < 2; ++ni) {
    int col = col0 + wn * 32 + ni * 16 + lm;
#pragma unroll
    for (int mi = 0; mi < 4; ++mi) {
      int rbase = row0 + wm * 64 + mi * 16 + lq * 4;
#pragma unroll
      for (int i = 0; i < 4; ++i) {
        int row = rbase + i;
        float v = acc[mi][ni][i] + (float)Zt[(size_t)row * U_N + col];
        v = v > 0.f ? v : 0.f;
        hout[(size_t)row * U_N + col] = (bf16)v;
        if (out) out[(size_t)row * U_N + col] = v;
      }
    }
  }
}

extern "C" void kernel_launch(void* const* d_in, const int* in_sizes, int n_in,
                              void* d_out, int out_size, void* d_ws, size_t ws_size,
                              hipStream_t stream) {
  const float* x    = (const float*)d_in[0];
  const float* W    = (const float*)d_in[1];
  const float* bias = (const float*)d_in[2];
  float* out = (float*)d_out;

  char* ws = (char*)d_ws;
  bf16* Wxb = (bf16*)ws;                               // 2 MB
  bf16* Whb = (bf16*)(ws + ((size_t)2 << 20));         // 2 MB
  bf16* h0  = (bf16*)(ws + ((size_t)4 << 20));         // 8 MB
  bf16* h1  = (bf16*)(ws + ((size_t)12 << 20));        // 8 MB
  bf16* Zb  = (bf16*)(ws + ((size_t)32 << 20));        // 293.6 MB (35*4096*1024 bf16)

  pack_w<<<1024, 256, 0, stream>>>(W, Wxb, Whb);
  hipMemsetAsync(h0, 0, (size_t)BU * sizeof(bf16), stream);

  // Z = x @ Wx^T + b for all t
  z_gemm<<<dim3(8, 1120), 256, 0, stream>>>(x, Wxb, bias, Zb);

  bf16* bufs[2] = { h0, h1 };
  for (int t = 0; t < T_N; ++t) {
    bf16* hin  = bufs[t & 1];
    bf16* hout = bufs[(t + 1) & 1];
    float* o   = (t == T_N - 1) ? out : nullptr;
    rnn_step<<<dim3(16, 32), 256, 0, stream>>>(hin, Whb, Zb + (size_t)t * BU, hout, o);
  }
}